// Round 1
// baseline (522.350 us; speedup 1.0000x reference)
//
#include <hip/hip_runtime.h>

#define B_SZ 8
#define T_SZ 2048
#define C_SZ 1024

#define BM 128
#define BN 128
#define BK 32
#define LDK 40  // padded LDS row stride (bf16 elems): 80B, keeps 16B alignment

typedef __attribute__((ext_vector_type(8))) short short8;
typedef __attribute__((ext_vector_type(8))) unsigned short ushort8;
typedef __attribute__((ext_vector_type(4))) float f32x4;

__device__ __forceinline__ unsigned short f2bf(float x) {
  union { float f; unsigned u; } v; v.f = x;
  unsigned r = v.u + 0x7FFFu + ((v.u >> 16) & 1u);  // RNE
  return (unsigned short)(r >> 16);
}
__device__ __forceinline__ float bf2f(unsigned short h) {
  union { unsigned u; float f; } v; v.u = ((unsigned)h) << 16;
  return v.f;
}

// ---------------------------------------------------------------------------
// Kernel 1: Y(bf16)[M,N] = x(fp32)[M,K] @ W(fp32)[K,N] + bias
// 128x128 tile, 4 waves (2x2), 16x16x32 bf16 MFMA, BK=32, single LDS buffer.
// ---------------------------------------------------------------------------
__global__ __launch_bounds__(256) void qkv_gemm(
    const float* __restrict__ A, const float* __restrict__ W,
    const float* __restrict__ bias, unsigned short* __restrict__ Y,
    int M, int N, int K) {
  __shared__ unsigned short As[BM * LDK] __attribute__((aligned(16)));
  __shared__ unsigned short Bs[BN * LDK] __attribute__((aligned(16)));
  const int m0 = blockIdx.y * BM;
  const int n0 = blockIdx.x * BN;
  const int t = threadIdx.x;
  const int lane = t & 63;
  const int wid = t >> 6;
  const int wm = (wid >> 1) * 64;
  const int wn = (wid & 1) * 64;
  const int fr = lane & 15;
  const int fq = lane >> 4;

  f32x4 acc[4][4] = {};

  const int arow = t >> 1;          // 0..127
  const int acol = (t & 1) * 16;    // 0 or 16
  const int bn_i = t & 127;         // col within B tile
  const int bk0 = (t >> 7) * 16;    // 0 or 16

  for (int k0 = 0; k0 < K; k0 += BK) {
    __syncthreads();
    {  // stage A: fp32 -> bf16, row-major [128][32]
      const float4* ap =
          (const float4*)(A + (size_t)(m0 + arow) * K + k0 + acol);
      float4 f0 = ap[0], f1 = ap[1], f2 = ap[2], f3 = ap[3];
      ushort8 u0, u1;
      u0[0] = f2bf(f0.x); u0[1] = f2bf(f0.y); u0[2] = f2bf(f0.z); u0[3] = f2bf(f0.w);
      u0[4] = f2bf(f1.x); u0[5] = f2bf(f1.y); u0[6] = f2bf(f1.z); u0[7] = f2bf(f1.w);
      u1[0] = f2bf(f2.x); u1[1] = f2bf(f2.y); u1[2] = f2bf(f2.z); u1[3] = f2bf(f2.w);
      u1[4] = f2bf(f3.x); u1[5] = f2bf(f3.y); u1[6] = f2bf(f3.z); u1[7] = f2bf(f3.w);
      *(ushort8*)&As[arow * LDK + acol] = u0;
      *(ushort8*)&As[arow * LDK + acol + 8] = u1;
    }
    {  // stage B transposed: Bs[n][k] = W[k0+k][n0+n]
      const float* bp = W + (size_t)(k0 + bk0) * N + n0 + bn_i;
      ushort8 u0, u1;
#pragma unroll
      for (int i = 0; i < 8; ++i) u0[i] = f2bf(bp[(size_t)i * N]);
#pragma unroll
      for (int i = 0; i < 8; ++i) u1[i] = f2bf(bp[(size_t)(i + 8) * N]);
      *(ushort8*)&Bs[bn_i * LDK + bk0] = u0;
      *(ushort8*)&Bs[bn_i * LDK + bk0 + 8] = u1;
    }
    __syncthreads();
    short8 af[4], bfr[4];
#pragma unroll
    for (int m = 0; m < 4; ++m)
      af[m] = *(const short8*)&As[(wm + m * 16 + fr) * LDK + fq * 8];
#pragma unroll
    for (int n = 0; n < 4; ++n)
      bfr[n] = *(const short8*)&Bs[(wn + n * 16 + fr) * LDK + fq * 8];
#pragma unroll
    for (int m = 0; m < 4; ++m)
#pragma unroll
      for (int n = 0; n < 4; ++n)
        acc[m][n] = __builtin_amdgcn_mfma_f32_16x16x32_bf16(af[m], bfr[n],
                                                            acc[m][n], 0, 0, 0);
  }

#pragma unroll
  for (int n = 0; n < 4; ++n) {
    const int col = n0 + wn + n * 16 + fr;
    const float bv = bias[col];
#pragma unroll
    for (int m = 0; m < 4; ++m) {
      const int rbase = m0 + wm + m * 16 + fq * 4;
#pragma unroll
      for (int j = 0; j < 4; ++j)
        Y[(size_t)(rbase + j) * N + col] = f2bf(acc[m][n][j] + bv);
    }
  }
}

// ---------------------------------------------------------------------------
// Kernel 2: S(bf16)[b,t,s] = scale * Q[b,t,:] . K[b,s,:]   (NT GEMM)
// Skips tiles entirely above the causal diagonal.
// ---------------------------------------------------------------------------
__global__ __launch_bounds__(256) void scores_gemm(
    const unsigned short* __restrict__ Q, const unsigned short* __restrict__ Km,
    unsigned short* __restrict__ S, float scale) {
  const int m0 = blockIdx.y * BM;  // t
  const int n0 = blockIdx.x * BN;  // s
  if (n0 > m0) return;             // whole tile above diagonal: never read
  const int b = blockIdx.z;
  const unsigned short* Qb = Q + (size_t)b * T_SZ * C_SZ;
  const unsigned short* Kb = Km + (size_t)b * T_SZ * C_SZ;

  __shared__ unsigned short As[BM * LDK] __attribute__((aligned(16)));
  __shared__ unsigned short Bs[BN * LDK] __attribute__((aligned(16)));
  const int t = threadIdx.x;
  const int lane = t & 63;
  const int wid = t >> 6;
  const int wm = (wid >> 1) * 64;
  const int wn = (wid & 1) * 64;
  const int fr = lane & 15;
  const int fq = lane >> 4;

  f32x4 acc[4][4] = {};
  const int arow = t >> 1;
  const int acol = (t & 1) * 16;

  for (int k0 = 0; k0 < C_SZ; k0 += BK) {
    __syncthreads();
    {
      const ushort8* qp =
          (const ushort8*)(Qb + (size_t)(m0 + arow) * C_SZ + k0 + acol);
      *(ushort8*)&As[arow * LDK + acol] = qp[0];
      *(ushort8*)&As[arow * LDK + acol + 8] = qp[1];
      const ushort8* kp =
          (const ushort8*)(Kb + (size_t)(n0 + arow) * C_SZ + k0 + acol);
      *(ushort8*)&Bs[arow * LDK + acol] = kp[0];
      *(ushort8*)&Bs[arow * LDK + acol + 8] = kp[1];
    }
    __syncthreads();
    short8 af[4], bfr[4];
#pragma unroll
    for (int m = 0; m < 4; ++m)
      af[m] = *(const short8*)&As[(wm + m * 16 + fr) * LDK + fq * 8];
#pragma unroll
    for (int n = 0; n < 4; ++n)
      bfr[n] = *(const short8*)&Bs[(wn + n * 16 + fr) * LDK + fq * 8];
#pragma unroll
    for (int m = 0; m < 4; ++m)
#pragma unroll
      for (int n = 0; n < 4; ++n)
        acc[m][n] = __builtin_amdgcn_mfma_f32_16x16x32_bf16(af[m], bfr[n],
                                                            acc[m][n], 0, 0, 0);
  }

  unsigned short* Sb = S + (size_t)b * T_SZ * T_SZ;
#pragma unroll
  for (int n = 0; n < 4; ++n) {
    const int col = n0 + wn + n * 16 + fr;
#pragma unroll
    for (int m = 0; m < 4; ++m) {
      const int rbase = m0 + wm + m * 16 + fq * 4;
#pragma unroll
      for (int j = 0; j < 4; ++j)
        Sb[(size_t)(rbase + j) * T_SZ + col] = f2bf(acc[m][n][j] * scale);
    }
  }
}

// ---------------------------------------------------------------------------
// Kernel 3: in-place causal softmax over S rows (bf16 in/out, fp32 math).
// Writes zeros for s in (t, roundup128(t+1)) so PV can read whole K-tiles.
// ---------------------------------------------------------------------------
__device__ __forceinline__ float wredmax(float v) {
#pragma unroll
  for (int o = 32; o > 0; o >>= 1) v = fmaxf(v, __shfl_xor(v, o, 64));
  return v;
}
__device__ __forceinline__ float wredsum(float v) {
#pragma unroll
  for (int o = 32; o > 0; o >>= 1) v += __shfl_xor(v, o, 64);
  return v;
}

__global__ __launch_bounds__(256) void softmax_causal(
    unsigned short* __restrict__ S) {
  const int row = blockIdx.x;  // [0, B*T)
  const int b = row >> 11;
  const int tq = row & (T_SZ - 1);
  unsigned short* sr = S + (size_t)b * T_SZ * T_SZ + (size_t)tq * T_SZ;
  const int len = tq + 1;
  const int wlen = (len + 127) & ~127;
  __shared__ float rowf[T_SZ];
  __shared__ float red[4];
  const int tid = threadIdx.x;
  const int lane = tid & 63;
  const int wid = tid >> 6;

  float mx = -1e30f;
  for (int i = tid; i < len; i += 256) {
    float v = bf2f(sr[i]);
    rowf[i] = v;
    mx = fmaxf(mx, v);
  }
  mx = wredmax(mx);
  if (lane == 0) red[wid] = mx;
  __syncthreads();
  mx = fmaxf(fmaxf(red[0], red[1]), fmaxf(red[2], red[3]));
  __syncthreads();

  float sm = 0.f;
  for (int i = tid; i < len; i += 256) {
    float e = __expf(rowf[i] - mx);
    rowf[i] = e;
    sm += e;
  }
  sm = wredsum(sm);
  if (lane == 0) red[wid] = sm;
  __syncthreads();
  sm = red[0] + red[1] + red[2] + red[3];
  const float inv = 1.f / sm;

  for (int i = tid; i < wlen; i += 256)
    sr[i] = (i < len) ? f2bf(rowf[i] * inv) : (unsigned short)0;
}

// ---------------------------------------------------------------------------
// Kernel 4: O(fp32)[b,t,c] = P(bf16)[b,t,:] @ V(bf16)[b,:,c]  (NN GEMM)
// Causal: K-loop capped at t0+128.
// ---------------------------------------------------------------------------
__global__ __launch_bounds__(256) void pv_gemm(
    const unsigned short* __restrict__ P, const unsigned short* __restrict__ V,
    float* __restrict__ O) {
  const int m0 = blockIdx.y * BM;  // t
  const int n0 = blockIdx.x * BN;  // c
  const int b = blockIdx.z;
  const unsigned short* Pb = P + (size_t)b * T_SZ * T_SZ;
  const unsigned short* Vb = V + (size_t)b * T_SZ * C_SZ;

  __shared__ unsigned short As[BM * LDK] __attribute__((aligned(16)));
  __shared__ unsigned short Bs[BN * LDK] __attribute__((aligned(16)));
  const int t = threadIdx.x;
  const int lane = t & 63;
  const int wid = t >> 6;
  const int wm = (wid >> 1) * 64;
  const int wn = (wid & 1) * 64;
  const int fr = lane & 15;
  const int fq = lane >> 4;

  f32x4 acc[4][4] = {};
  const int arow = t >> 1;
  const int acol = (t & 1) * 16;
  const int bn_i = t & 127;
  const int bk0 = (t >> 7) * 16;
  const int kmax = m0 + BM;  // causal cap

  for (int k0 = 0; k0 < kmax; k0 += BK) {
    __syncthreads();
    {
      const ushort8* pp =
          (const ushort8*)(Pb + (size_t)(m0 + arow) * T_SZ + k0 + acol);
      *(ushort8*)&As[arow * LDK + acol] = pp[0];
      *(ushort8*)&As[arow * LDK + acol + 8] = pp[1];
    }
    {  // stage V transposed: Bs[c][s]
      const unsigned short* bp =
          Vb + (size_t)(k0 + bk0) * C_SZ + n0 + bn_i;
      ushort8 u0, u1;
#pragma unroll
      for (int i = 0; i < 8; ++i) u0[i] = bp[(size_t)i * C_SZ];
#pragma unroll
      for (int i = 0; i < 8; ++i) u1[i] = bp[(size_t)(i + 8) * C_SZ];
      *(ushort8*)&Bs[bn_i * LDK + bk0] = u0;
      *(ushort8*)&Bs[bn_i * LDK + bk0 + 8] = u1;
    }
    __syncthreads();
    short8 af[4], bfr[4];
#pragma unroll
    for (int m = 0; m < 4; ++m)
      af[m] = *(const short8*)&As[(wm + m * 16 + fr) * LDK + fq * 8];
#pragma unroll
    for (int n = 0; n < 4; ++n)
      bfr[n] = *(const short8*)&Bs[(wn + n * 16 + fr) * LDK + fq * 8];
#pragma unroll
    for (int m = 0; m < 4; ++m)
#pragma unroll
      for (int n = 0; n < 4; ++n)
        acc[m][n] = __builtin_amdgcn_mfma_f32_16x16x32_bf16(af[m], bfr[n],
                                                            acc[m][n], 0, 0, 0);
  }

#pragma unroll
  for (int n = 0; n < 4; ++n) {
    const int col = n0 + wn + n * 16 + fr;
#pragma unroll
    for (int m = 0; m < 4; ++m) {
      const int rbase = m0 + wm + m * 16 + fq * 4;
#pragma unroll
      for (int j = 0; j < 4; ++j)
        O[(size_t)b * T_SZ * C_SZ + (size_t)(rbase + j) * C_SZ + col] =
            acc[m][n][j];
    }
  }
}

// ---------------------------------------------------------------------------
extern "C" void kernel_launch(void* const* d_in, const int* in_sizes, int n_in,
                              void* d_out, int out_size, void* d_ws,
                              size_t ws_size, hipStream_t stream) {
  (void)in_sizes; (void)n_in; (void)out_size; (void)ws_size;
  const float* x = (const float*)d_in[0];
  const float* Wq = (const float*)d_in[1];
  const float* bq = (const float*)d_in[2];
  const float* Wk = (const float*)d_in[3];
  const float* bk = (const float*)d_in[4];
  const float* Wv = (const float*)d_in[5];
  const float* bv = (const float*)d_in[6];
  float* out = (float*)d_out;

  const size_t TC = (size_t)B_SZ * T_SZ * C_SZ;  // 16,777,216
  unsigned short* Q = (unsigned short*)d_ws;
  unsigned short* K = Q + TC;
  unsigned short* V = K + TC;
  unsigned short* S = V + TC;  // B*T*T bf16

  const float scale = 0.022097086912079608f;  // 2048^-0.5

  dim3 blk(256);
  dim3 g1(C_SZ / BN, (B_SZ * T_SZ) / BM);  // 8 x 128
  hipLaunchKernelGGL(qkv_gemm, g1, blk, 0, stream, x, Wq, bq, Q,
                     B_SZ * T_SZ, C_SZ, C_SZ);
  hipLaunchKernelGGL(qkv_gemm, g1, blk, 0, stream, x, Wk, bk, K,
                     B_SZ * T_SZ, C_SZ, C_SZ);
  hipLaunchKernelGGL(qkv_gemm, g1, blk, 0, stream, x, Wv, bv, V,
                     B_SZ * T_SZ, C_SZ, C_SZ);

  dim3 g2(T_SZ / BN, T_SZ / BM, B_SZ);  // 16 x 16 x 8
  hipLaunchKernelGGL(scores_gemm, g2, blk, 0, stream, Q, K, S, scale);

  hipLaunchKernelGGL(softmax_causal, dim3(B_SZ * T_SZ), blk, 0, stream, S);

  dim3 g3(C_SZ / BN, T_SZ / BM, B_SZ);  // 8 x 16 x 8
  hipLaunchKernelGGL(pv_gemm, g3, blk, 0, stream, S, V, out);
}

// Round 2
// 377.940 us; speedup vs baseline: 1.3821x; 1.3821x over previous
//
#include <hip/hip_runtime.h>

#define B_SZ 8
#define T_SZ 2048
#define C_SZ 1024

typedef __attribute__((ext_vector_type(8))) short short8;
typedef __attribute__((ext_vector_type(8))) unsigned short ushort8;
typedef __attribute__((ext_vector_type(4))) float f32x4;

__device__ __forceinline__ unsigned short f2bf(float x) {
  union { float f; unsigned u; } v; v.f = x;
  unsigned r = v.u + 0x7FFFu + ((v.u >> 16) & 1u);  // RNE
  return (unsigned short)(r >> 16);
}
__device__ __forceinline__ float bf2f(unsigned short h) {
  union { unsigned u; float f; } v; v.u = ((unsigned)h) << 16;
  return v.f;
}

// async global->LDS, 16B per lane; LDS base must be wave-uniform (HW writes
// base + lane*16), global pointer is per-lane.
__device__ __forceinline__ void gload16(const void* g, void* l) {
  __builtin_amdgcn_global_load_lds(
      (const __attribute__((address_space(1))) unsigned int*)(uintptr_t)g,
      (__attribute__((address_space(3))) unsigned int*)(uintptr_t)l, 16, 0, 0);
}

// ---------------------------------------------------------------------------
// Shared NT-GEMM core (m97 structure): C[128][128] tile, BK=32, 4 waves (2x2),
// 16x16x32 bf16 MFMA, linear LDS [128][32], global_load_lds dwordx4 staging.
// A[M][K], B[N][K] both k-contiguous; Ab/Bb pre-offset to the tile origin.
// ---------------------------------------------------------------------------
template <int LDA, int LDB>
__device__ __forceinline__ void nt_core(const unsigned short* __restrict__ Ab,
                                        const unsigned short* __restrict__ Bb,
                                        int kend, unsigned short* As,
                                        unsigned short* Bs, f32x4 (&acc)[4][4]) {
  const int t = threadIdx.x;
  const int lane = t & 63;
  const int wid = t >> 6;
  const int wm = (wid >> 1) * 64;
  const int wn = (wid & 1) * 64;
  const int fr = lane & 15;
  const int fq = lane >> 4;
  const int srow = lane >> 2;       // row within 16-row chunk
  const int scol = (lane & 3) * 8;  // bf16 col offset (16B per lane)

  for (int k0 = 0; k0 < kend; k0 += 32) {
    __syncthreads();
#pragma unroll
    for (int i = 0; i < 2; ++i) {
      const int ch = wid * 2 + i;  // 8 chunks of 16 rows cover 128 rows
      gload16(Ab + (size_t)(ch * 16 + srow) * LDA + k0 + scol, As + ch * 512);
      gload16(Bb + (size_t)(ch * 16 + srow) * LDB + k0 + scol, Bs + ch * 512);
    }
    __syncthreads();
    short8 af[4], bfr[4];
#pragma unroll
    for (int m = 0; m < 4; ++m)
      af[m] = *(const short8*)&As[(wm + m * 16 + fr) * 32 + fq * 8];
#pragma unroll
    for (int n = 0; n < 4; ++n)
      bfr[n] = *(const short8*)&Bs[(wn + n * 16 + fr) * 32 + fq * 8];
#pragma unroll
    for (int m = 0; m < 4; ++m)
#pragma unroll
      for (int n = 0; n < 4; ++n)
        acc[m][n] = __builtin_amdgcn_mfma_f32_16x16x32_bf16(af[m], bfr[n],
                                                            acc[m][n], 0, 0, 0);
  }
}

// ---------------------------------------------------------------------------
// Kernel: x fp32 -> bf16
// ---------------------------------------------------------------------------
__global__ __launch_bounds__(256) void convert_x(const float* __restrict__ x,
                                                 unsigned short* __restrict__ Xb,
                                                 int n8) {
  for (int i = blockIdx.x * blockDim.x + threadIdx.x; i < n8;
       i += gridDim.x * blockDim.x) {
    const float4* p = (const float4*)(x + (size_t)i * 8);
    float4 a = p[0], b = p[1];
    ushort8 u;
    u[0] = f2bf(a.x); u[1] = f2bf(a.y); u[2] = f2bf(a.z); u[3] = f2bf(a.w);
    u[4] = f2bf(b.x); u[5] = f2bf(b.y); u[6] = f2bf(b.z); u[7] = f2bf(b.w);
    *(ushort8*)(Xb + (size_t)i * 8) = u;
  }
}

// ---------------------------------------------------------------------------
// Kernel: W fp32 [K][N] -> Wt bf16 [N][K] (transpose+convert), z picks matrix
// ---------------------------------------------------------------------------
__global__ __launch_bounds__(256) void transpose_w(
    const float* __restrict__ Wq, const float* __restrict__ Wk,
    const float* __restrict__ Wv, unsigned short* __restrict__ Wt) {
  const int z = blockIdx.z;
  const float* W = z == 0 ? Wq : (z == 1 ? Wk : Wv);
  unsigned short* O = Wt + (size_t)z * C_SZ * C_SZ;
  __shared__ float tl[32][33];
  const int bx = blockIdx.x * 32;  // n
  const int by = blockIdx.y * 32;  // k
  const int tx = threadIdx.x & 31;
  const int ty = threadIdx.x >> 5;  // 0..7
#pragma unroll
  for (int j = 0; j < 4; ++j)
    tl[ty + j * 8][tx] = W[(size_t)(by + ty + j * 8) * C_SZ + bx + tx];
  __syncthreads();
#pragma unroll
  for (int j = 0; j < 4; ++j)
    O[(size_t)(bx + ty + j * 8) * C_SZ + by + tx] = f2bf(tl[tx][ty + j * 8]);
}

// ---------------------------------------------------------------------------
// Kernel: V bf16 [T][C] -> Vt bf16 [C][T] per batch
// ---------------------------------------------------------------------------
__global__ __launch_bounds__(256) void transpose_v(
    const unsigned short* __restrict__ V, unsigned short* __restrict__ Vt) {
  const int b = blockIdx.z;
  __shared__ unsigned short tl[64][66];
  const int bx = blockIdx.x * 64;  // c
  const int by = blockIdx.y * 64;  // t
  const int tx = threadIdx.x & 63;
  const int ty = threadIdx.x >> 6;  // 0..3
  const unsigned short* Vb = V + (size_t)b * T_SZ * C_SZ;
  unsigned short* Ob = Vt + (size_t)b * C_SZ * T_SZ;
#pragma unroll
  for (int r = 0; r < 16; ++r)
    tl[ty * 16 + r][tx] = Vb[(size_t)(by + ty * 16 + r) * C_SZ + bx + tx];
  __syncthreads();
#pragma unroll
  for (int r = 0; r < 16; ++r)
    Ob[(size_t)(bx + ty * 16 + r) * T_SZ + by + tx] = tl[tx][ty * 16 + r];
}

// ---------------------------------------------------------------------------
// Kernel: fused QKV GEMM. Y_z = Xb @ Wt_z^T + b_z, bf16 out. grid.z = matrix.
// ---------------------------------------------------------------------------
__global__ __launch_bounds__(256) void qkv_fused(
    const unsigned short* __restrict__ Xb, const unsigned short* __restrict__ Wt,
    const float* __restrict__ bq, const float* __restrict__ bk,
    const float* __restrict__ bv, unsigned short* __restrict__ QKV) {
  __shared__ unsigned short As[128 * 32] __attribute__((aligned(16)));
  __shared__ unsigned short Bs[128 * 32] __attribute__((aligned(16)));
  const int z = blockIdx.z;
  const int m0 = blockIdx.y * 128;
  const int n0 = blockIdx.x * 128;
  const float* bias = z == 0 ? bq : (z == 1 ? bk : bv);

  f32x4 acc[4][4] = {};
  nt_core<C_SZ, C_SZ>(Xb + (size_t)m0 * C_SZ,
                      Wt + (size_t)z * C_SZ * C_SZ + (size_t)n0 * C_SZ, C_SZ,
                      As, Bs, acc);

  unsigned short* Y = QKV + (size_t)z * B_SZ * T_SZ * C_SZ;
  const int lane = threadIdx.x & 63;
  const int wid = threadIdx.x >> 6;
  const int wm = (wid >> 1) * 64, wn = (wid & 1) * 64;
  const int fr = lane & 15, fq = lane >> 4;
#pragma unroll
  for (int n = 0; n < 4; ++n) {
    const int col = n0 + wn + n * 16 + fr;
    const float bvv = bias[col];
#pragma unroll
    for (int m = 0; m < 4; ++m) {
      const int rb = m0 + wm + m * 16 + fq * 4;
#pragma unroll
      for (int j = 0; j < 4; ++j)
        Y[(size_t)(rb + j) * C_SZ + col] = f2bf(acc[m][n][j] + bvv);
    }
  }
}

// ---------------------------------------------------------------------------
// Kernel: S = scale * Q @ K^T (causal block skip), bf16 out
// ---------------------------------------------------------------------------
__global__ __launch_bounds__(256) void scores_gemm(
    const unsigned short* __restrict__ Q, const unsigned short* __restrict__ Km,
    unsigned short* __restrict__ S, float scale) {
  const int m0 = blockIdx.y * 128;  // t
  const int n0 = blockIdx.x * 128;  // s
  if (n0 > m0) return;
  const int b = blockIdx.z;
  __shared__ unsigned short As[128 * 32] __attribute__((aligned(16)));
  __shared__ unsigned short Bs[128 * 32] __attribute__((aligned(16)));

  f32x4 acc[4][4] = {};
  nt_core<C_SZ, C_SZ>(Q + (size_t)b * T_SZ * C_SZ + (size_t)m0 * C_SZ,
                      Km + (size_t)b * T_SZ * C_SZ + (size_t)n0 * C_SZ, C_SZ,
                      As, Bs, acc);

  unsigned short* Sb = S + (size_t)b * T_SZ * T_SZ;
  const int lane = threadIdx.x & 63;
  const int wid = threadIdx.x >> 6;
  const int wm = (wid >> 1) * 64, wn = (wid & 1) * 64;
  const int fr = lane & 15, fq = lane >> 4;
#pragma unroll
  for (int n = 0; n < 4; ++n) {
    const int col = n0 + wn + n * 16 + fr;
#pragma unroll
    for (int m = 0; m < 4; ++m) {
      const int rb = m0 + wm + m * 16 + fq * 4;
#pragma unroll
      for (int j = 0; j < 4; ++j)
        Sb[(size_t)(rb + j) * T_SZ + col] = f2bf(acc[m][n][j] * scale);
    }
  }
}

// ---------------------------------------------------------------------------
// Kernel: causal softmax in place (bf16, fp32 math); zero-pads to next 128.
// ---------------------------------------------------------------------------
__device__ __forceinline__ float wredmax(float v) {
#pragma unroll
  for (int o = 32; o > 0; o >>= 1) v = fmaxf(v, __shfl_xor(v, o, 64));
  return v;
}
__device__ __forceinline__ float wredsum(float v) {
#pragma unroll
  for (int o = 32; o > 0; o >>= 1) v += __shfl_xor(v, o, 64);
  return v;
}

__global__ __launch_bounds__(256) void softmax_causal(
    unsigned short* __restrict__ S) {
  const int row = blockIdx.x;
  const int b = row >> 11;
  const int tq = row & (T_SZ - 1);
  unsigned short* sr = S + (size_t)b * T_SZ * T_SZ + (size_t)tq * T_SZ;
  const int len = tq + 1;
  const int wlen = (len + 127) & ~127;
  __shared__ float rowf[T_SZ];
  __shared__ float red[4];
  const int tid = threadIdx.x;
  const int lane = tid & 63;
  const int wid = tid >> 6;

  float mx = -1e30f;
  for (int i = tid; i < len; i += 256) {
    float v = bf2f(sr[i]);
    rowf[i] = v;
    mx = fmaxf(mx, v);
  }
  mx = wredmax(mx);
  if (lane == 0) red[wid] = mx;
  __syncthreads();
  mx = fmaxf(fmaxf(red[0], red[1]), fmaxf(red[2], red[3]));
  __syncthreads();

  float sm = 0.f;
  for (int i = tid; i < len; i += 256) {
    float e = __expf(rowf[i] - mx);
    rowf[i] = e;
    sm += e;
  }
  sm = wredsum(sm);
  if (lane == 0) red[wid] = sm;
  __syncthreads();
  sm = red[0] + red[1] + red[2] + red[3];
  const float inv = 1.f / sm;

  for (int i = tid; i < wlen; i += 256)
    sr[i] = (i < len) ? f2bf(rowf[i] * inv) : (unsigned short)0;
}

// ---------------------------------------------------------------------------
// Kernel: O = P @ Vt^T (NT, causal K-cap), fp32 out
// ---------------------------------------------------------------------------
__global__ __launch_bounds__(256) void pv_gemm(
    const unsigned short* __restrict__ P, const unsigned short* __restrict__ Vt,
    float* __restrict__ O) {
  const int m0 = blockIdx.y * 128;  // t
  const int n0 = blockIdx.x * 128;  // c
  const int b = blockIdx.z;
  __shared__ unsigned short As[128 * 32] __attribute__((aligned(16)));
  __shared__ unsigned short Bs[128 * 32] __attribute__((aligned(16)));

  f32x4 acc[4][4] = {};
  nt_core<T_SZ, T_SZ>(P + (size_t)b * T_SZ * T_SZ + (size_t)m0 * T_SZ,
                      Vt + (size_t)b * C_SZ * T_SZ + (size_t)n0 * T_SZ,
                      m0 + 128, As, Bs, acc);

  float* Ob = O + (size_t)b * T_SZ * C_SZ;
  const int lane = threadIdx.x & 63;
  const int wid = threadIdx.x >> 6;
  const int wm = (wid >> 1) * 64, wn = (wid & 1) * 64;
  const int fr = lane & 15, fq = lane >> 4;
#pragma unroll
  for (int n = 0; n < 4; ++n) {
    const int col = n0 + wn + n * 16 + fr;
#pragma unroll
    for (int m = 0; m < 4; ++m) {
      const int rb = m0 + wm + m * 16 + fq * 4;
#pragma unroll
      for (int j = 0; j < 4; ++j)
        Ob[(size_t)(rb + j) * C_SZ + col] = acc[m][n][j];
    }
  }
}

// ---------------------------------------------------------------------------
extern "C" void kernel_launch(void* const* d_in, const int* in_sizes, int n_in,
                              void* d_out, int out_size, void* d_ws,
                              size_t ws_size, hipStream_t stream) {
  (void)in_sizes; (void)n_in; (void)out_size; (void)ws_size;
  const float* x = (const float*)d_in[0];
  const float* Wq = (const float*)d_in[1];
  const float* bq = (const float*)d_in[2];
  const float* Wk = (const float*)d_in[3];
  const float* bk = (const float*)d_in[4];
  const float* Wv = (const float*)d_in[5];
  const float* bv = (const float*)d_in[6];
  float* out = (float*)d_out;

  const size_t TC = (size_t)B_SZ * T_SZ * C_SZ;  // 16,777,216
  unsigned short* Q = (unsigned short*)d_ws;     // also QKV base; later Vt
  unsigned short* K = Q + TC;
  unsigned short* V = K + TC;
  unsigned short* S = V + TC;   // B*T*T = 33.5M ushorts
  unsigned short* Xb = S;       // phase-1 alias (dead once scores runs)
  unsigned short* Wt = S + TC;  // phase-1 alias, 3M ushorts
  unsigned short* Vt = Q;       // phase-2 alias (Q dead after scores)

  const float scale = 0.022097086912079608f;  // 2048^-0.5
  dim3 blk(256);

  hipLaunchKernelGGL(convert_x, dim3(2048), blk, 0, stream, x, Xb,
                     (int)(TC / 8));
  hipLaunchKernelGGL(transpose_w, dim3(32, 32, 3), blk, 0, stream, Wq, Wk, Wv,
                     Wt);
  hipLaunchKernelGGL(qkv_fused, dim3(8, 128, 3), blk, 0, stream, Xb, Wt, bq,
                     bk, bv, Q);
  hipLaunchKernelGGL(scores_gemm, dim3(16, 16, 8), blk, 0, stream, Q, K, S,
                     scale);
  hipLaunchKernelGGL(transpose_v, dim3(16, 32, 8), blk, 0, stream, V, Vt);
  hipLaunchKernelGGL(softmax_causal, dim3(B_SZ * T_SZ), blk, 0, stream, S);
  hipLaunchKernelGGL(pv_gemm, dim3(8, 16, 8), blk, 0, stream, S, Vt, out);
}

// Round 3
// 301.252 us; speedup vs baseline: 1.7339x; 1.2546x over previous
//
#include <hip/hip_runtime.h>

#define B_SZ 8
#define T_SZ 2048
#define C_SZ 1024

typedef __attribute__((ext_vector_type(8))) short short8;
typedef __attribute__((ext_vector_type(8))) unsigned short ushort8;
typedef __attribute__((ext_vector_type(4))) float f32x4;

__device__ __forceinline__ unsigned short f2bf(float x) {
  union { float f; unsigned u; } v; v.f = x;
  unsigned r = v.u + 0x7FFFu + ((v.u >> 16) & 1u);  // RNE
  return (unsigned short)(r >> 16);
}
__device__ __forceinline__ float bf2f(unsigned short h) {
  union { unsigned u; float f; } v; v.u = ((unsigned)h) << 16;
  return v.f;
}

// async global->LDS, 16B/lane; LDS base wave-uniform, global addr per-lane.
__device__ __forceinline__ void gload16(const void* g, void* l) {
  __builtin_amdgcn_global_load_lds(
      (const __attribute__((address_space(1))) unsigned int*)(uintptr_t)g,
      (__attribute__((address_space(3))) unsigned int*)(uintptr_t)l, 16, 0, 0);
}

// T1: bijective XCD-chunked swizzle (m204 form). orig%8 = XCD; gives each XCD
// a contiguous chunk of logical tile ids -> L2 panel reuse stays on-XCD.
__device__ __forceinline__ int xcd_swz(int orig, int nwg) {
  const int q = nwg >> 3, r = nwg & 7;
  const int xcd = orig & 7, off = orig >> 3;
  return (xcd < r ? xcd * (q + 1) : r * (q + 1) + (xcd - r) * q) + off;
}

// ---------------------------------------------------------------------------
// 2-phase double-buffered NT-GEMM core. 128x128 tile, BK=32, 4 waves (2x2),
// 16x16x32 bf16 MFMA, linear LDS [128][32] x2 buffers, global_load_lds x16B.
// One __syncthreads per K-step; stage[k+1] issued BEFORE compute[k] so the
// async loads complete under the MFMAs (minimum T3 pipeline).
// ---------------------------------------------------------------------------
template <int LDA, int LDB>
__device__ __forceinline__ void nt_core2(const unsigned short* __restrict__ Ab,
                                         const unsigned short* __restrict__ Bb,
                                         int kend, unsigned short* As,
                                         unsigned short* Bs,
                                         f32x4 (&acc)[4][4]) {
  const int t = threadIdx.x;
  const int lane = t & 63;
  const int wid = t >> 6;
  const int wm = (wid >> 1) * 64;
  const int wn = (wid & 1) * 64;
  const int fr = lane & 15;
  const int fq = lane >> 4;
  const int srow = lane >> 2;       // row within 16-row chunk
  const int scol = (lane & 3) * 8;  // bf16 col offset (16B per lane)

  // prologue: stage k0=0 into buffer 0
#pragma unroll
  for (int i = 0; i < 2; ++i) {
    const int ch = wid * 2 + i;
    gload16(Ab + (size_t)(ch * 16 + srow) * LDA + scol, As + ch * 512);
    gload16(Bb + (size_t)(ch * 16 + srow) * LDB + scol, Bs + ch * 512);
  }
  __syncthreads();

  int cur = 0;
  for (int k0 = 32; k0 < kend; k0 += 32) {
    const int nxt = cur ^ 1;
#pragma unroll
    for (int i = 0; i < 2; ++i) {
      const int ch = wid * 2 + i;
      gload16(Ab + (size_t)(ch * 16 + srow) * LDA + k0 + scol,
              As + nxt * 4096 + ch * 512);
      gload16(Bb + (size_t)(ch * 16 + srow) * LDB + k0 + scol,
              Bs + nxt * 4096 + ch * 512);
    }
    short8 af[4], bfr[4];
#pragma unroll
    for (int m = 0; m < 4; ++m)
      af[m] =
          *(const short8*)&As[cur * 4096 + (wm + m * 16 + fr) * 32 + fq * 8];
#pragma unroll
    for (int n = 0; n < 4; ++n)
      bfr[n] =
          *(const short8*)&Bs[cur * 4096 + (wn + n * 16 + fr) * 32 + fq * 8];
#pragma unroll
    for (int m = 0; m < 4; ++m)
#pragma unroll
      for (int n = 0; n < 4; ++n)
        acc[m][n] = __builtin_amdgcn_mfma_f32_16x16x32_bf16(af[m], bfr[n],
                                                            acc[m][n], 0, 0, 0);
    __syncthreads();  // drains vmcnt(0) (prefetch) + lgkmcnt, then barrier
    cur = nxt;
  }
  {  // final tile
    short8 af[4], bfr[4];
#pragma unroll
    for (int m = 0; m < 4; ++m)
      af[m] =
          *(const short8*)&As[cur * 4096 + (wm + m * 16 + fr) * 32 + fq * 8];
#pragma unroll
    for (int n = 0; n < 4; ++n)
      bfr[n] =
          *(const short8*)&Bs[cur * 4096 + (wn + n * 16 + fr) * 32 + fq * 8];
#pragma unroll
    for (int m = 0; m < 4; ++m)
#pragma unroll
      for (int n = 0; n < 4; ++n)
        acc[m][n] = __builtin_amdgcn_mfma_f32_16x16x32_bf16(af[m], bfr[n],
                                                            acc[m][n], 0, 0, 0);
  }
}

// ---------------------------------------------------------------------------
// Kernel: x fp32 -> bf16
// ---------------------------------------------------------------------------
__global__ __launch_bounds__(256) void convert_x(const float* __restrict__ x,
                                                 unsigned short* __restrict__ Xb,
                                                 int n8) {
  for (int i = blockIdx.x * blockDim.x + threadIdx.x; i < n8;
       i += gridDim.x * blockDim.x) {
    const float4* p = (const float4*)(x + (size_t)i * 8);
    float4 a = p[0], b = p[1];
    ushort8 u;
    u[0] = f2bf(a.x); u[1] = f2bf(a.y); u[2] = f2bf(a.z); u[3] = f2bf(a.w);
    u[4] = f2bf(b.x); u[5] = f2bf(b.y); u[6] = f2bf(b.z); u[7] = f2bf(b.w);
    *(ushort8*)(Xb + (size_t)i * 8) = u;
  }
}

// ---------------------------------------------------------------------------
// Kernel: W fp32 [K][N] -> Wt bf16 [N][K] (transpose+convert), z picks matrix
// ---------------------------------------------------------------------------
__global__ __launch_bounds__(256) void transpose_w(
    const float* __restrict__ Wq, const float* __restrict__ Wk,
    const float* __restrict__ Wv, unsigned short* __restrict__ Wt) {
  const int z = blockIdx.z;
  const float* W = z == 0 ? Wq : (z == 1 ? Wk : Wv);
  unsigned short* O = Wt + (size_t)z * C_SZ * C_SZ;
  __shared__ float tl[32][33];
  const int bx = blockIdx.x * 32;  // n
  const int by = blockIdx.y * 32;  // k
  const int tx = threadIdx.x & 31;
  const int ty = threadIdx.x >> 5;  // 0..7
#pragma unroll
  for (int j = 0; j < 4; ++j)
    tl[ty + j * 8][tx] = W[(size_t)(by + ty + j * 8) * C_SZ + bx + tx];
  __syncthreads();
#pragma unroll
  for (int j = 0; j < 4; ++j)
    O[(size_t)(bx + ty + j * 8) * C_SZ + by + tx] = f2bf(tl[tx][ty + j * 8]);
}

// ---------------------------------------------------------------------------
// Kernel: V bf16 [T][C] -> Vt bf16 [C][T] per batch
// ---------------------------------------------------------------------------
__global__ __launch_bounds__(256) void transpose_v(
    const unsigned short* __restrict__ V, unsigned short* __restrict__ Vt) {
  const int b = blockIdx.z;
  __shared__ unsigned short tl[64][66];
  const int bx = blockIdx.x * 64;  // c
  const int by = blockIdx.y * 64;  // t
  const int tx = threadIdx.x & 63;
  const int ty = threadIdx.x >> 6;  // 0..3
  const unsigned short* Vb = V + (size_t)b * T_SZ * C_SZ;
  unsigned short* Ob = Vt + (size_t)b * C_SZ * T_SZ;
#pragma unroll
  for (int r = 0; r < 16; ++r)
    tl[ty * 16 + r][tx] = Vb[(size_t)(by + ty * 16 + r) * C_SZ + bx + tx];
  __syncthreads();
#pragma unroll
  for (int r = 0; r < 16; ++r)
    Ob[(size_t)(bx + ty * 16 + r) * T_SZ + by + tx] = tl[tx][ty * 16 + r];
}

// ---------------------------------------------------------------------------
// Kernel: fused QKV GEMM, flat grid + XCD swizzle. Y_z = Xb @ Wt_z^T + b_z.
// Logical id: z*1024 + m_t*8 + n_t (n fastest -> 8 neighbors share A-panel,
// Wt_z (2MB) stays hot in the XCD's L2).
// ---------------------------------------------------------------------------
__global__ __launch_bounds__(256) void qkv_fused(
    const unsigned short* __restrict__ Xb, const unsigned short* __restrict__ Wt,
    const float* __restrict__ bq, const float* __restrict__ bk,
    const float* __restrict__ bv, unsigned short* __restrict__ QKV) {
  __shared__ unsigned short As[2 * 4096] __attribute__((aligned(16)));
  __shared__ unsigned short Bs[2 * 4096] __attribute__((aligned(16)));
  const int wg = xcd_swz(blockIdx.x, 3 * 128 * 8);
  const int z = wg >> 10;
  const int rem = wg & 1023;
  const int m0 = (rem >> 3) * 128;
  const int n0 = (rem & 7) * 128;
  const float* bias = z == 0 ? bq : (z == 1 ? bk : bv);

  f32x4 acc[4][4] = {};
  nt_core2<C_SZ, C_SZ>(Xb + (size_t)m0 * C_SZ,
                       Wt + (size_t)z * C_SZ * C_SZ + (size_t)n0 * C_SZ, C_SZ,
                       As, Bs, acc);

  unsigned short* Y = QKV + (size_t)z * B_SZ * T_SZ * C_SZ;
  const int lane = threadIdx.x & 63;
  const int wid = threadIdx.x >> 6;
  const int wm = (wid >> 1) * 64, wn = (wid & 1) * 64;
  const int fr = lane & 15, fq = lane >> 4;
#pragma unroll
  for (int n = 0; n < 4; ++n) {
    const int col = n0 + wn + n * 16 + fr;
    const float bvv = bias[col];
#pragma unroll
    for (int m = 0; m < 4; ++m) {
      const int rb = m0 + wm + m * 16 + fq * 4;
#pragma unroll
      for (int j = 0; j < 4; ++j)
        Y[(size_t)(rb + j) * C_SZ + col] = f2bf(acc[m][n][j] + bvv);
    }
  }
}

// ---------------------------------------------------------------------------
// Kernel: S = scale * Q @ K^T (causal block skip), flat grid + XCD swizzle
// ---------------------------------------------------------------------------
__global__ __launch_bounds__(256) void scores_gemm(
    const unsigned short* __restrict__ Q, const unsigned short* __restrict__ Km,
    unsigned short* __restrict__ S, float scale) {
  const int wg = xcd_swz(blockIdx.x, B_SZ * 16 * 16);
  const int b = wg >> 8;
  const int rem = wg & 255;
  const int m0 = (rem >> 4) * 128;  // t
  const int n0 = (rem & 15) * 128;  // s
  if (n0 > m0) return;
  __shared__ unsigned short As[2 * 4096] __attribute__((aligned(16)));
  __shared__ unsigned short Bs[2 * 4096] __attribute__((aligned(16)));

  f32x4 acc[4][4] = {};
  nt_core2<C_SZ, C_SZ>(Q + (size_t)b * T_SZ * C_SZ + (size_t)m0 * C_SZ,
                       Km + (size_t)b * T_SZ * C_SZ + (size_t)n0 * C_SZ, C_SZ,
                       As, Bs, acc);

  unsigned short* Sb = S + (size_t)b * T_SZ * T_SZ;
  const int lane = threadIdx.x & 63;
  const int wid = threadIdx.x >> 6;
  const int wm = (wid >> 1) * 64, wn = (wid & 1) * 64;
  const int fr = lane & 15, fq = lane >> 4;
#pragma unroll
  for (int n = 0; n < 4; ++n) {
    const int col = n0 + wn + n * 16 + fr;
#pragma unroll
    for (int m = 0; m < 4; ++m) {
      const int rb = m0 + wm + m * 16 + fq * 4;
#pragma unroll
      for (int j = 0; j < 4; ++j)
        Sb[(size_t)(rb + j) * T_SZ + col] = f2bf(acc[m][n][j] * scale);
    }
  }
}

// ---------------------------------------------------------------------------
// Kernel: causal softmax, vectorized ushort8 (one row per block, row in regs)
// ---------------------------------------------------------------------------
__device__ __forceinline__ float wredmax(float v) {
#pragma unroll
  for (int o = 32; o > 0; o >>= 1) v = fmaxf(v, __shfl_xor(v, o, 64));
  return v;
}
__device__ __forceinline__ float wredsum(float v) {
#pragma unroll
  for (int o = 32; o > 0; o >>= 1) v += __shfl_xor(v, o, 64);
  return v;
}

__global__ __launch_bounds__(256) void softmax_causal(
    unsigned short* __restrict__ S) {
  const int row = blockIdx.x;
  const int b = row >> 11;
  const int tq = row & (T_SZ - 1);
  unsigned short* sr = S + (size_t)b * T_SZ * T_SZ + (size_t)tq * T_SZ;
  const int len = tq + 1;
  const int wlen = (len + 127) & ~127;
  const int tid = threadIdx.x;
  const int lane = tid & 63;
  const int wid = tid >> 6;
  const int i0 = tid * 8;
  __shared__ float red[4];

  const ushort8 raw = *(const ushort8*)(sr + i0);  // row is full 2048 alloc
  float v[8];
  float mx = -1e30f;
#pragma unroll
  for (int j = 0; j < 8; ++j) {
    v[j] = (i0 + j < len) ? bf2f(raw[j]) : -1e30f;
    mx = fmaxf(mx, v[j]);
  }
  mx = wredmax(mx);
  if (lane == 0) red[wid] = mx;
  __syncthreads();
  mx = fmaxf(fmaxf(red[0], red[1]), fmaxf(red[2], red[3]));
  __syncthreads();

  float sm = 0.f;
#pragma unroll
  for (int j = 0; j < 8; ++j) {
    v[j] = __expf(v[j] - mx);  // masked lanes: exp(-huge) == 0
    sm += v[j];
  }
  sm = wredsum(sm);
  if (lane == 0) red[wid] = sm;
  __syncthreads();
  sm = red[0] + red[1] + red[2] + red[3];
  const float inv = 1.f / sm;

  if (i0 < wlen) {
    ushort8 o;
#pragma unroll
    for (int j = 0; j < 8; ++j)
      o[j] = (i0 + j < len) ? f2bf(v[j] * inv) : (unsigned short)0;
    *(ushort8*)(sr + i0) = o;
  }
}

// ---------------------------------------------------------------------------
// Kernel: O = P @ Vt^T (NT, causal K-cap), flat grid + XCD swizzle, fp32 out
// ---------------------------------------------------------------------------
__global__ __launch_bounds__(256) void pv_gemm(
    const unsigned short* __restrict__ P, const unsigned short* __restrict__ Vt,
    float* __restrict__ O) {
  const int wg = xcd_swz(blockIdx.x, B_SZ * 16 * 8);
  const int b = wg >> 7;
  const int rem = wg & 127;
  const int m0 = (rem >> 3) * 128;  // t
  const int n0 = (rem & 7) * 128;   // c
  __shared__ unsigned short As[2 * 4096] __attribute__((aligned(16)));
  __shared__ unsigned short Bs[2 * 4096] __attribute__((aligned(16)));

  f32x4 acc[4][4] = {};
  nt_core2<T_SZ, T_SZ>(P + (size_t)b * T_SZ * T_SZ + (size_t)m0 * T_SZ,
                       Vt + (size_t)b * C_SZ * T_SZ + (size_t)n0 * T_SZ,
                       m0 + 128, As, Bs, acc);

  float* Ob = O + (size_t)b * T_SZ * C_SZ;
  const int lane = threadIdx.x & 63;
  const int wid = threadIdx.x >> 6;
  const int wm = (wid >> 1) * 64, wn = (wid & 1) * 64;
  const int fr = lane & 15, fq = lane >> 4;
#pragma unroll
  for (int n = 0; n < 4; ++n) {
    const int col = n0 + wn + n * 16 + fr;
#pragma unroll
    for (int m = 0; m < 4; ++m) {
      const int rb = m0 + wm + m * 16 + fq * 4;
#pragma unroll
      for (int j = 0; j < 4; ++j)
        Ob[(size_t)(rb + j) * C_SZ + col] = acc[m][n][j];
    }
  }
}

// ---------------------------------------------------------------------------
extern "C" void kernel_launch(void* const* d_in, const int* in_sizes, int n_in,
                              void* d_out, int out_size, void* d_ws,
                              size_t ws_size, hipStream_t stream) {
  (void)in_sizes; (void)n_in; (void)out_size; (void)ws_size;
  const float* x = (const float*)d_in[0];
  const float* Wq = (const float*)d_in[1];
  const float* bq = (const float*)d_in[2];
  const float* Wk = (const float*)d_in[3];
  const float* bk = (const float*)d_in[4];
  const float* Wv = (const float*)d_in[5];
  const float* bv = (const float*)d_in[6];
  float* out = (float*)d_out;

  const size_t TC = (size_t)B_SZ * T_SZ * C_SZ;  // 16,777,216
  unsigned short* Q = (unsigned short*)d_ws;     // QKV base; later Vt
  unsigned short* K = Q + TC;
  unsigned short* V = K + TC;
  unsigned short* S = V + TC;   // B*T*T ushorts
  unsigned short* Xb = S;       // phase-1 alias (dead once scores runs)
  unsigned short* Wt = S + TC;  // phase-1 alias, 3M ushorts
  unsigned short* Vt = Q;       // phase-2 alias (Q dead after scores)

  const float scale = 0.022097086912079608f;  // 2048^-0.5
  dim3 blk(256);

  hipLaunchKernelGGL(convert_x, dim3(2048), blk, 0, stream, x, Xb,
                     (int)(TC / 8));
  hipLaunchKernelGGL(transpose_w, dim3(32, 32, 3), blk, 0, stream, Wq, Wk, Wv,
                     Wt);
  hipLaunchKernelGGL(qkv_fused, dim3(3 * 128 * 8), blk, 0, stream, Xb, Wt, bq,
                     bk, bv, Q);
  hipLaunchKernelGGL(scores_gemm, dim3(B_SZ * 16 * 16), blk, 0, stream, Q, K,
                     S, scale);
  hipLaunchKernelGGL(transpose_v, dim3(16, 32, 8), blk, 0, stream, V, Vt);
  hipLaunchKernelGGL(softmax_causal, dim3(B_SZ * T_SZ), blk, 0, stream, S);
  hipLaunchKernelGGL(pv_gemm, dim3(B_SZ * 16 * 8), blk, 0, stream, S, Vt, out);
}